// Round 8
// baseline (320.354 us; speedup 1.0000x reference)
//
#include <hip/hip_runtime.h>
#include <hip/hip_bf16.h>

#define HID 128
#define BSH 6            // 64 nodes per bucket
#define MAXBUCK 2048     // >= ceil(n/64); n=100000 -> 1563
#define NTILE 8          // 16 cols (32 B) per tile -> 3.2 MB/tile, fits XCD L2

__device__ __forceinline__ float b2f(unsigned short u) {
    union { unsigned i; float f; } v; v.i = ((unsigned)u) << 16; return v.f;
}
__device__ __forceinline__ unsigned short f2b(float f) {
    unsigned u = __float_as_uint(f);
    return (unsigned short)((u + 0x7fffu + ((u >> 16) & 1u)) >> 16);  // RNE
}

// ---------------- zero bucket counters ----------------
__global__ void zero_kernel(unsigned* __restrict__ p, int n) {
    int i = blockIdx.x * blockDim.x + threadIdx.x;
    if (i < n) p[i] = 0u;
}

// ---------------- K1: bucket histogram (LDS-aggregated) ----------------
__global__ __launch_bounds__(256) void bincount_kernel(const int* __restrict__ ei,
                                                       unsigned* __restrict__ bcount,
                                                       int E, int n, int nbuck) {
    __shared__ unsigned hist[MAXBUCK];
    for (int i = threadIdx.x; i < nbuck; i += 256) hist[i] = 0u;
    __syncthreads();
    int i = blockIdx.x * 256 + threadIdx.x, stride = gridDim.x * 256;
    for (; i < E; i += stride) {
        int dst = ei[(size_t)E + i];
        if ((unsigned)dst < (unsigned)n) atomicAdd(&hist[dst >> BSH], 1u);
    }
    __syncthreads();
    for (int b = threadIdx.x; b < nbuck; b += 256) {
        unsigned c = hist[b];
        if (c) atomicAdd(&bcount[b], c);
    }
}

// ---------------- K2: scan of bucket counts (single block) ----------------
__global__ __launch_bounds__(1024) void bscan_kernel(const unsigned* __restrict__ bcount,
                                                     unsigned* __restrict__ boff,
                                                     unsigned* __restrict__ bwoff,
                                                     unsigned* __restrict__ off,
                                                     int nbuck, int n) {
    __shared__ unsigned sums[1024];
    int t = threadIdx.x;
    int chunk = (nbuck + 1023) >> 10;
    int beg = min(t * chunk, nbuck), end = min(beg + chunk, nbuck);
    unsigned local = 0;
    for (int i = beg; i < end; ++i) local += bcount[i];
    sums[t] = local;
    __syncthreads();
    for (int d = 1; d < 1024; d <<= 1) {
        unsigned v = (t >= d) ? sums[t - d] : 0u;
        __syncthreads();
        sums[t] += v;
        __syncthreads();
    }
    unsigned run = (t > 0) ? sums[t - 1] : 0u;
    for (int i = beg; i < end; ++i) { boff[i] = run; bwoff[i] = run; run += bcount[i]; }
    if (t == 1023) { boff[nbuck] = sums[1023]; off[n] = sums[1023]; }
}

// ---------------- K3 (fused): binscatter (blocks 0..nsb-1) + gemm (rest) ----------------
// binned[pos] = (dst&63)<<20 | src ; gemm: hp = (x+h_cur)@W[:,0:128] bf16 TILED [8][n][16]
__global__ __launch_bounds__(256) void phase3_kernel(const int* __restrict__ ei,
                                                     unsigned* __restrict__ bwoff,
                                                     unsigned* __restrict__ binned,
                                                     const float* __restrict__ x,
                                                     const float* __restrict__ hc,
                                                     const float* __restrict__ W,
                                                     unsigned short* __restrict__ hp,
                                                     int E, int n, int nbuck, int nsb) {
    __shared__ union {
        struct { unsigned hist[MAXBUCK]; unsigned base[MAXBUCK]; } bs;
        float A[64 * 132];
    } sm;

    if (blockIdx.x < nsb) {
        // ---- binscatter body ----
        int chunk = (E + nsb - 1) / nsb;
        int beg = blockIdx.x * chunk, end = min(E, beg + chunk);
        for (int i = threadIdx.x; i < nbuck; i += 256) sm.bs.hist[i] = 0u;
        __syncthreads();
        for (int i = beg + threadIdx.x; i < end; i += 256) {
            int dst = ei[(size_t)E + i];
            if ((unsigned)dst < (unsigned)n) atomicAdd(&sm.bs.hist[dst >> BSH], 1u);
        }
        __syncthreads();
        for (int b = threadIdx.x; b < nbuck; b += 256) {
            unsigned c = sm.bs.hist[b];
            sm.bs.base[b] = c ? atomicAdd(&bwoff[b], c) : 0u;
            sm.bs.hist[b] = 0u;
        }
        __syncthreads();
        for (int i = beg + threadIdx.x; i < end; i += 256) {
            int s = ei[i];
            int dst = ei[(size_t)E + i];
            if ((unsigned)dst >= (unsigned)n) continue;
            unsigned ss = (unsigned)min(max(s, 0), n - 1);
            int b = dst >> BSH;
            unsigned r = atomicAdd(&sm.bs.hist[b], 1u);
            binned[sm.bs.base[b] + r] = ss | ((unsigned)(dst & ((1 << BSH) - 1)) << 20);
        }
    } else {
        // ---- gemm body, tiled hp output ----
        int tid = threadIdx.x;
        int r0 = (blockIdx.x - nsb) * 64;

        for (int i = tid; i < 2048; i += 256) {
            int row = i >> 5;
            int c4 = (i & 31) * 4;
            int grow = r0 + row;
            float4 v;
            if (grow < n) {
                float4 a = *(const float4*)(x + (size_t)grow * HID + c4);
                float4 bb = *(const float4*)(hc + (size_t)grow * HID + c4);
                v = make_float4(a.x + bb.x, a.y + bb.y, a.z + bb.z, a.w + bb.w);
            } else {
                v = make_float4(0.f, 0.f, 0.f, 0.f);
            }
            *(float4*)(&sm.A[row * 132 + c4]) = v;
        }
        __syncthreads();

        int cg = tid & 31;
        int c4 = cg * 4;
        int rg = tid >> 5;
        float acc[8][4];
#pragma unroll
        for (int r = 0; r < 8; ++r) {
            acc[r][0] = 0.f; acc[r][1] = 0.f; acc[r][2] = 0.f; acc[r][3] = 0.f;
        }

#pragma unroll 4
        for (int k = 0; k < 128; ++k) {
            float4 w = *(const float4*)(W + (size_t)k * 512 + c4);
#pragma unroll
            for (int r = 0; r < 8; ++r) {
                float a = sm.A[(rg * 8 + r) * 132 + k];
                acc[r][0] += a * w.x;
                acc[r][1] += a * w.y;
                acc[r][2] += a * w.z;
                acc[r][3] += a * w.w;
            }
        }

        size_t tile = (size_t)(c4 >> 4);
        int cin = c4 & 15;
#pragma unroll
        for (int r = 0; r < 8; ++r) {
            int grow = r0 + rg * 8 + r;
            if (grow < n) {
                unsigned long long pack =
                    (unsigned long long)f2b(acc[r][0]) |
                    ((unsigned long long)f2b(acc[r][1]) << 16) |
                    ((unsigned long long)f2b(acc[r][2]) << 32) |
                    ((unsigned long long)f2b(acc[r][3]) << 48);
                *(unsigned long long*)(hp + tile * (size_t)n * 16 + (size_t)grow * 16 + cin) = pack;
            }
        }
    }
}

// ---------------- K4: per-bucket CSR finalize + in-place dinv scaling of tiled hp ----------------
__global__ __launch_bounds__(256) void csrbuild_kernel(const unsigned* __restrict__ binned,
                                                       const unsigned* __restrict__ boff,
                                                       unsigned* __restrict__ off,
                                                       float* __restrict__ dinv,
                                                       unsigned* __restrict__ srcs,
                                                       unsigned short* __restrict__ hp,
                                                       int n) {
    __shared__ unsigned hist[64];
    __shared__ unsigned nodeoff[64];
    __shared__ float sdinv[64];
    int b = blockIdx.x;
    unsigned s0 = boff[b], s1 = boff[b + 1];
    int t = threadIdx.x;
    if (t < 64) hist[t] = 0u;
    __syncthreads();
    for (unsigned j = s0 + t; j < s1; j += 256) atomicAdd(&hist[binned[j] >> 20], 1u);
    __syncthreads();
    if (t < 64) {  // wave 0: 64-lane shuffle scan
        unsigned cnt = hist[t];
        unsigned x = cnt;
        for (int d = 1; d < 64; d <<= 1) {
            unsigned v = __shfl_up(x, d, 64);
            if (t >= d) x += v;
        }
        unsigned excl = x - cnt;
        nodeoff[t] = excl;
        hist[t] = 0u;
        float dv = rsqrtf((float)(cnt + 1u));  // +1 self-loop
        sdinv[t] = dv;
        int node = (b << BSH) + t;
        if (node < n) {
            off[node] = s0 + excl;
            dinv[node] = dv;
        }
    }
    __syncthreads();
    for (unsigned j = s0 + t; j < s1; j += 256) {
        unsigned p = binned[j];
        unsigned dl = p >> 20, s = p & 0xFFFFFu;
        unsigned r = atomicAdd(&hist[dl], 1u);
        srcs[s0 + nodeoff[dl] + r] = s;
    }
    // scale this bucket's hp rows by dinv across all 8 tiles (64 nodes x 8 u32 per tile)
    int node0 = b << BSH;
    unsigned* hp32 = (unsigned*)hp;
    size_t tstride = (size_t)n * 8;  // u32 per tile
    for (int idx = t; idx < 4096; idx += 256) {
        int t8 = idx >> 9;           // tile 0..7
        int rem = idx & 511;
        int ndl = rem >> 3;          // node-local 0..63
        int wq = rem & 7;            // u32 within 32B tile-row
        int nd = node0 + ndl;
        if (nd < n) {
            float dv = sdinv[ndl];
            unsigned* p = hp32 + (size_t)t8 * tstride + (size_t)nd * 8 + wq;
            unsigned u = *p;
            float lo = b2f((unsigned short)(u & 0xFFFFu)) * dv;
            float hi = b2f((unsigned short)(u >> 16)) * dv;
            *p = (unsigned)f2b(lo) | ((unsigned)f2b(hi) << 16);
        }
    }
}

// ---------------- aggregate: XCD-pinned tiles, lane = (node, colpair), reg accum ----------------
// tile = blockIdx & 7 (round-robin -> fixed XCD); block = 32 nodes x one tile.
// Each lane owns one node's 2 cols: no cross-lane reduce; 8-deep pipelined edge loop.
__global__ __launch_bounds__(256) void agg_tiled_kernel(const unsigned* __restrict__ srcs,
                                                        const unsigned* __restrict__ off,
                                                        const float* __restrict__ dinv,
                                                        const unsigned short* __restrict__ hp,
                                                        const float* __restrict__ b,
                                                        float* __restrict__ out, int n) {
    int blk = blockIdx.x;
    int t = blk & 7;
    int grp = blk >> 3;
    int tid = threadIdx.x;
    int w = tid >> 6;            // wave 0..3
    int lane = tid & 63;
    int ndw = lane >> 3;         // node slot 0..7
    int cp = lane & 7;           // col pair 0..7
    int node = grp * 32 + w * 8 + ndw;
    bool valid = node < n;
    int nd = valid ? node : (n - 1);
    const unsigned short* hpt = hp + (size_t)t * n * 16;

    unsigned base = off[nd];
    unsigned cnt = valid ? (off[nd + 1] - base) : 0u;

    float ax = 0.f, ay = 0.f;
    unsigned k = 0;
    for (; k + 8 <= cnt; k += 8) {
        unsigned s[8]; unsigned v[8];
#pragma unroll
        for (int j = 0; j < 8; ++j) s[j] = srcs[base + k + j];
#pragma unroll
        for (int j = 0; j < 8; ++j) v[j] = *(const unsigned*)(hpt + (size_t)s[j] * 16 + cp * 2);
#pragma unroll
        for (int j = 0; j < 8; ++j) {
            ax += b2f((unsigned short)(v[j] & 0xFFFFu));
            ay += b2f((unsigned short)(v[j] >> 16));
        }
    }
    if (k < cnt) {  // masked clamped tail, keeps 8 loads in flight
        unsigned last = cnt - 1;
        unsigned s[8]; unsigned v[8]; float m[8];
#pragma unroll
        for (int j = 0; j < 8; ++j) {
            unsigned jj = k + j;
            m[j] = (jj < cnt) ? 1.f : 0.f;
            s[j] = srcs[base + (jj < cnt ? jj : last)];
        }
#pragma unroll
        for (int j = 0; j < 8; ++j) v[j] = *(const unsigned*)(hpt + (size_t)s[j] * 16 + cp * 2);
#pragma unroll
        for (int j = 0; j < 8; ++j) {
            ax = fmaf(m[j], b2f((unsigned short)(v[j] & 0xFFFFu)), ax);
            ay = fmaf(m[j], b2f((unsigned short)(v[j] >> 16)), ay);
        }
    }

    if (valid) {
        // self-loop (hp pre-scaled by dinv) + bias
        unsigned vd = *(const unsigned*)(hpt + (size_t)nd * 16 + cp * 2);
        ax += b2f((unsigned short)(vd & 0xFFFFu));
        ay += b2f((unsigned short)(vd >> 16));
        float di = dinv[nd];
        int col = t * 16 + cp * 2;
        float2 bb = *(const float2*)(b + col);
        float2 res = make_float2(di * ax + bb.x, di * ay + bb.y);
        *(float2*)(out + (size_t)nd * HID + col) = res;
    }
}

extern "C" void kernel_launch(void* const* d_in, const int* in_sizes, int n_in,
                              void* d_out, int out_size, void* d_ws, size_t ws_size,
                              hipStream_t stream) {
    const float* x = (const float*)d_in[0];
    const int* ei = (const int*)d_in[1];       // int32 per harness contract
    const float* hc = (const float*)d_in[2];
    // d_in[3] = c_cur unused
    const float* W = (const float*)d_in[4];
    const float* b = (const float*)d_in[5];
    float* out = (float*)d_out;

    int n = in_sizes[0] / HID;      // 100000
    int E = in_sizes[1] / 2;        // 3200000
    int nbuck = (n + 63) >> BSH;    // 1563 (<= MAXBUCK)
    int nsb = 256;                  // binscatter blocks in fused phase3

    // workspace layout (16B-aligned), total ~39.2 MB
    char* ws = (char*)d_ws;
    unsigned* bcount = (unsigned*)(ws);                    // 8KB region
    unsigned* boff   = (unsigned*)(ws + 8192);             // 8KB region (nbuck+1)
    unsigned* bwoff  = (unsigned*)(ws + 16384);            // 8KB region
    unsigned* off    = (unsigned*)(ws + 24576);            // (n+1)*4
    float*    dinv   = (float*)   (ws + 424592);           // n*4
    unsigned* srcs   = (unsigned*)(ws + 824592);           // E*4 = 12.8MB
    unsigned short* hp = (unsigned short*)(ws + 13624592); // [8][n][16] bf16 = 25.6MB

    // d_out doubles as scratch for the packed binned edges (12.8MB << 51.2MB);
    // agg_tiled_kernel fully overwrites d_out afterwards.
    unsigned* binned = (unsigned*)d_out;

    zero_kernel<<<(nbuck + 255) / 256, 256, 0, stream>>>(bcount, nbuck);
    bincount_kernel<<<512, 256, 0, stream>>>(ei, bcount, E, n, nbuck);
    bscan_kernel<<<1, 1024, 0, stream>>>(bcount, boff, bwoff, off, nbuck, n);

    int gemm_blocks = (n + 63) / 64;   // 1563
    phase3_kernel<<<nsb + gemm_blocks, 256, 0, stream>>>(ei, bwoff, binned, x, hc, W, hp,
                                                         E, n, nbuck, nsb);
    csrbuild_kernel<<<nbuck, 256, 0, stream>>>(binned, boff, off, dinv, srcs, hp, n);

    int ngrp = (n + 31) / 32;          // 3125
    agg_tiled_kernel<<<ngrp * NTILE, 256, 0, stream>>>(srcs, off, dinv, hp, b, out, n);
}